// Round 2
// baseline (1053.660 us; speedup 1.0000x reference)
//
#include <hip/hip_runtime.h>
#include <hip/hip_bf16.h>

// Bahdanau additive attention, B=256 L=1024 D=H=U=512, fp32 in/out.
// score[b,l] = V . tanh(features[b,l,:]@W1 + (hidden[b]@W2 + W2b + W1b))   (+V_b: no-op under softmax)
// out = concat(context [B,512], weights [B,1024])
//
// Plan: W1 -> bf16 transposed (k-contiguous per output column) once; proj_h in fp32;
// fused bf16-MFMA GEMM + tanh + V-dot per 128-row tile (never materialize [B,L,U]);
// softmax + weighted feature sum per batch row.

typedef short bf16x8 __attribute__((ext_vector_type(8)));
typedef float f32x4 __attribute__((ext_vector_type(4)));

__device__ __forceinline__ unsigned short f2bf(float x) {
  __hip_bfloat16 h = __float2bfloat16(x);
  union { __hip_bfloat16 h; unsigned short u; } c; c.h = h;
  return c.u;
}

__device__ __forceinline__ float tanh_fast(float x) {
  // tanh(x) = 1 - 2/(e^{2x}+1); exp overflow->inf->+1, underflow->0->-1 : correct saturation
  float e = __expf(2.0f * x);
  return 1.0f - 2.0f * __builtin_amdgcn_rcpf(e + 1.0f);
}

// ---------------- kernel 1: W1 [512 k][512 n] fp32 -> W1T [n][k] bf16 ----------------
__global__ __launch_bounds__(256)
void k_w1t(const float* __restrict__ W1, unsigned short* __restrict__ W1T) {
  __shared__ unsigned short tile[64][65];
  const int k0 = (blockIdx.x & 7) * 64;
  const int n0 = (blockIdx.x >> 3) * 64;
  const int t = threadIdx.x;
#pragma unroll
  for (int i = 0; i < 16; ++i) {
    const int idx = t + i * 256;
    const int kk = idx >> 6, nn = idx & 63;
    tile[nn][kk] = f2bf(W1[(k0 + kk) * 512 + n0 + nn]);
  }
  __syncthreads();
#pragma unroll
  for (int i = 0; i < 16; ++i) {
    const int idx = t + i * 256;
    const int nn = idx >> 6, kk = idx & 63;
    W1T[(n0 + nn) * 512 + k0 + kk] = tile[nn][kk];
  }
}

// ---------------- kernel 2: ph[b,u] = W2b[u]+W1b[u] + sum_h hidden[b,h]*W2[h,u] ----------------
__global__ __launch_bounds__(512)
void k_ph(const float* __restrict__ hidden, const float* __restrict__ W2,
          const float* __restrict__ W2b, const float* __restrict__ W1b,
          float* __restrict__ ph) {
  __shared__ float hl[512];
  const int b = blockIdx.x, t = threadIdx.x;
  hl[t] = hidden[b * 512 + t];
  __syncthreads();
  float acc = W2b[t] + W1b[t];
#pragma unroll 8
  for (int h = 0; h < 512; ++h) acc = fmaf(hl[h], W2[h * 512 + t], acc);
  ph[b * 512 + t] = acc;
}

// ---------------- kernel 3: fused scores ----------------
// grid (8, 256): blockIdx.x = 128-row l-tile, blockIdx.y = b. 512 threads = 8 waves,
// wave w owns rows [w*16, w*16+16). LDS: A-tile [128][512] bf16 XOR-swizzled (131072 B)
// + W1T chunk [64 n][88 k] bf16 x2 double-buffered (pad 88 -> 2-way max on reads)
// + ph/V (4096 B) = 157696 B dynamic.
__global__ __launch_bounds__(512)
void k_scores(const float* __restrict__ feat,
              const unsigned short* __restrict__ W1T,
              const float* __restrict__ ph,
              const float* __restrict__ Vw,
              float* __restrict__ scores) {
  extern __shared__ char smem[];
  char* As  = smem;                      // [128][512] bf16, byte ^= (row&7)<<4
  char* Bs0 = smem + 131072;             // [64][88] bf16
  char* Bs1 = smem + 131072 + 11264;
  float* phl = (float*)(smem + 131072 + 22528);
  float* vl  = phl + 512;

  const int b = blockIdx.y;
  const int l0 = blockIdx.x * 128;
  const int t = threadIdx.x;
  const int lane = t & 63;
  const int w = t >> 6;

  phl[t] = ph[b * 512 + t];
  vl[t]  = Vw[t];

  // stage features tile fp32 -> bf16, swizzled
  {
    const float* fb = feat + ((size_t)b * 1024 + l0) * 512;
    const int c = t & 127;   // float4 chunk in row (512 floats = 128 chunks)
    const int r0 = t >> 7;   // 0..3
#pragma unroll
    for (int i = 0; i < 32; ++i) {
      const int r = r0 + i * 4;
      const float4 f4 = *(const float4*)(fb + r * 512 + c * 4);
      unsigned long long pk =
          (unsigned long long)f2bf(f4.x) |
          ((unsigned long long)f2bf(f4.y) << 16) |
          ((unsigned long long)f2bf(f4.z) << 32) |
          ((unsigned long long)f2bf(f4.w) << 48);
      const int byte = (r * 1024 + c * 8) ^ ((r & 7) << 4);
      *(unsigned long long*)(As + byte) = pk;
    }
  }

  float partial[4] = {0.f, 0.f, 0.f, 0.f};
  const int mrow = w * 16;
  const int arow = mrow + (lane & 15);
  const int kgrp = (lane >> 4) << 3;   // 0,8,16,24
  const int nn = t >> 3;               // Bs staging row
  const int kc = (t & 7) * 8;          // Bs staging k chunk

  for (int n0 = 0; n0 < 512; n0 += 64) {
    f32x4 acc0 = {0,0,0,0}, acc1 = {0,0,0,0}, acc2 = {0,0,0,0}, acc3 = {0,0,0,0};
    // prologue: stage k0=0 into Bs0 (safe: Bs0's last readers were retired by the
    // barrier at the top of the previous n0's final k-step; first n0 is pre-barrier anyway)
    {
      const uint4 d = *(const uint4*)(W1T + (size_t)(n0 + nn) * 512 + kc);
      *(uint4*)(Bs0 + nn * 176 + kc * 2) = d;
    }
    int cur = 0;
    for (int k0 = 0; k0 < 512; k0 += 64) {
      // issue next-chunk global load before the barrier: latency hides under barrier wait
      uint4 d;
      const bool pre = (k0 + 64) < 512;
      if (pre) d = *(const uint4*)(W1T + (size_t)(n0 + nn) * 512 + (k0 + 64) + kc);
      __syncthreads();   // staged buf `cur` visible; prior readers of buf cur^1 retired
      if (pre) *(uint4*)((cur ? Bs0 : Bs1) + nn * 176 + kc * 2) = d;
      const char* Bc = cur ? Bs1 : Bs0;
#pragma unroll
      for (int kk = 0; kk < 2; ++kk) {
        const int kb = kk * 32 + kgrp;
        const int abyte = ((arow * 1024) + (k0 + kb) * 2) ^ ((arow & 7) << 4);
        const bf16x8 af = *(const bf16x8*)(As + abyte);
        const int bb = (lane & 15) * 176 + kb * 2;
        const bf16x8 bf0 = *(const bf16x8*)(Bc + bb);
        const bf16x8 bf1 = *(const bf16x8*)(Bc + bb + 16 * 176);
        const bf16x8 bf2 = *(const bf16x8*)(Bc + bb + 32 * 176);
        const bf16x8 bf3 = *(const bf16x8*)(Bc + bb + 48 * 176);
        acc0 = __builtin_amdgcn_mfma_f32_16x16x32_bf16(af, bf0, acc0, 0, 0, 0);
        acc1 = __builtin_amdgcn_mfma_f32_16x16x32_bf16(af, bf1, acc1, 0, 0, 0);
        acc2 = __builtin_amdgcn_mfma_f32_16x16x32_bf16(af, bf2, acc2, 0, 0, 0);
        acc3 = __builtin_amdgcn_mfma_f32_16x16x32_bf16(af, bf3, acc3, 0, 0, 0);
      }
      cur ^= 1;
    }
    // epilogue: D layout col = lane&15, row = (lane>>4)*4 + rr  [m89-verified]
#pragma unroll
    for (int nf = 0; nf < 4; ++nf) {
      const f32x4 a = nf == 0 ? acc0 : nf == 1 ? acc1 : nf == 2 ? acc2 : acc3;
      const int col = n0 + nf * 16 + (lane & 15);
      const float vv = vl[col];
      const float pp = phl[col];
#pragma unroll
      for (int rr = 0; rr < 4; ++rr)
        partial[rr] = fmaf(vv, tanh_fast(a[rr] + pp), partial[rr]);
    }
  }

  // sum the 16 columns spread across lanes (lane&15 varies, lane>>4 = row group fixed)
#pragma unroll
  for (int m = 1; m <= 8; m <<= 1) {
#pragma unroll
    for (int rr = 0; rr < 4; ++rr)
      partial[rr] += __shfl_xor(partial[rr], m, 64);
  }
  if ((lane & 15) == 0) {
    const int rbase = l0 + mrow + ((lane >> 4) << 2);
    float4 sv = make_float4(partial[0], partial[1], partial[2], partial[3]);
    *(float4*)(scores + b * 1024 + rbase) = sv;
  }
}

// ---------------- kernel 4: softmax over L + context = sum_l w[l]*features[b,l,:] ----------------
__global__ __launch_bounds__(512)
void k_soft_ctx(const float* __restrict__ feat, const float* __restrict__ scores,
                float* __restrict__ out_ctx, float* __restrict__ out_w) {
  __shared__ float sl[1024];
  __shared__ float red[8];
  __shared__ float cl[2048];
  const int b = blockIdx.x;
  const int t = threadIdx.x;
  const int lane = t & 63;
  const int w = t >> 6;
  const float s0 = scores[b * 1024 + t];
  const float s1 = scores[b * 1024 + 512 + t];
  float m = fmaxf(s0, s1);
#pragma unroll
  for (int o = 32; o; o >>= 1) m = fmaxf(m, __shfl_xor(m, o, 64));
  if (lane == 0) red[w] = m;
  __syncthreads();
  m = red[0];
#pragma unroll
  for (int i = 1; i < 8; ++i) m = fmaxf(m, red[i]);
  const float e0 = __expf(s0 - m);
  const float e1 = __expf(s1 - m);
  float s = e0 + e1;
#pragma unroll
  for (int o = 32; o; o >>= 1) s += __shfl_xor(s, o, 64);
  __syncthreads();           // everyone done reading red (max)
  if (lane == 0) red[w] = s;
  __syncthreads();
  s = 0.f;
#pragma unroll
  for (int i = 0; i < 8; ++i) s += red[i];
  const float inv = 1.0f / s;
  const float w0 = e0 * inv, w1 = e1 * inv;
  out_w[b * 1024 + t] = w0;
  out_w[b * 1024 + 512 + t] = w1;
  sl[t] = w0;
  sl[t + 512] = w1;
  __syncthreads();

  const int d4 = (t & 127) * 4;   // d = d4..d4+3
  const int lq = t >> 7;          // l-quarter
  const float* fb = feat + (size_t)b * 1024 * 512;
  float4 acc = {0.f, 0.f, 0.f, 0.f};
#pragma unroll 4
  for (int i = 0; i < 256; ++i) {
    const int l = lq * 256 + i;
    const float4 f = *(const float4*)(fb + (size_t)l * 512 + d4);
    const float wl = sl[l];
    acc.x = fmaf(wl, f.x, acc.x);
    acc.y = fmaf(wl, f.y, acc.y);
    acc.z = fmaf(wl, f.z, acc.z);
    acc.w = fmaf(wl, f.w, acc.w);
  }
  *(float4*)&cl[lq * 512 + d4] = acc;
  __syncthreads();
  if (t < 128) {
    float4 r        = *(float4*)&cl[t * 4];
    const float4 a1 = *(float4*)&cl[512 + t * 4];
    const float4 a2 = *(float4*)&cl[1024 + t * 4];
    const float4 a3 = *(float4*)&cl[1536 + t * 4];
    r.x += a1.x + a2.x + a3.x;
    r.y += a1.y + a2.y + a3.y;
    r.z += a1.z + a2.z + a3.z;
    r.w += a1.w + a2.w + a3.w;
    *(float4*)&out_ctx[b * 512 + t * 4] = r;
  }
}

extern "C" void kernel_launch(void* const* d_in, const int* in_sizes, int n_in,
                              void* d_out, int out_size, void* d_ws, size_t ws_size,
                              hipStream_t stream) {
  const float* feat   = (const float*)d_in[0];
  const float* hidden = (const float*)d_in[1];
  const float* W1w    = (const float*)d_in[2];
  const float* W1b    = (const float*)d_in[3];
  const float* W2w    = (const float*)d_in[4];
  const float* W2b    = (const float*)d_in[5];
  const float* Vw     = (const float*)d_in[6];
  // d_in[7] = V_b: uniform score shift, softmax-invariant -> intentionally unused.
  float* out = (float*)d_out;

  // ws layout: W1T bf16 512KB | ph fp32 512KB | scores fp32 1MB  (2 MB total)
  unsigned short* W1T = (unsigned short*)d_ws;
  float* ph     = (float*)((char*)d_ws + 524288);
  float* scores = (float*)((char*)d_ws + 1048576);

  hipLaunchKernelGGL(k_w1t, dim3(64), dim3(256), 0, stream, W1w, W1T);
  hipLaunchKernelGGL(k_ph, dim3(256), dim3(512), 0, stream, hidden, W2w, W2b, W1b, ph);
  const int smem = 131072 + 22528 + 4096;   // 157696 B < 160 KiB
  hipFuncSetAttribute((const void*)k_scores, hipFuncAttributeMaxDynamicSharedMemorySize, smem);
  hipLaunchKernelGGL(k_scores, dim3(8, 256), dim3(512), smem, stream,
                     feat, W1T, ph, Vw, scores);
  hipLaunchKernelGGL(k_soft_ctx, dim3(256), dim3(512), 0, stream,
                     feat, scores, out, out + 256 * 512);
}